// Round 5
// baseline (102.548 us; speedup 1.0000x reference)
//
#include <hip/hip_runtime.h>

// Pool4d: x [b=2, c=8, l=16, d=32, h=64, w=64] f32
// kernel (3,3,3,3), stride (1,2,2,2), VALID, divide by 81.
// out [2, 8, 14, 15, 31, 31] f32.
//
// R5: paired-wo threads. Each thread produces outputs (wo, wo+1) for
// wo = 2*tw; their w-windows [4tw, 4tw+4] share a 16B-aligned float4 +
// one scalar -> per-output VMEM count halves, lane stride = 16B (perfectly
// coalesced). Keeps: XCD-chunked bijective swizzle, NT output stores,
// full-l fusion (14 temporal outputs per thread).

#define BC   16          // b*c
#define L_IN 16
#define D_IN 32
#define H_IN 64
#define W_IN 64
#define L_O  14
#define D_O  15
#define H_O  31
#define W_O  31
#define NPAIR 16                     // ceil(W_O/2)
#define SP_OUT (D_O * H_O * W_O)     // 14415
#define SP_IN  (D_IN * H_IN * W_IN)  // 131072

__global__ __launch_bounds__(256)
void pool4d_pair(const float* __restrict__ x, float* __restrict__ out) {
    // Bijective XCD-chunked swizzle (m204).
    int nwg = gridDim.x;
    int xcd = blockIdx.x & 7;
    int pos = blockIdx.x >> 3;
    int q = nwg >> 3, r = nwg & 7;
    int wg = (xcd < r ? xcd * (q + 1) : r * (q + 1) + (xcd - r) * q) + pos;

    int idx = wg * blockDim.x + threadIdx.x;
    const int total = BC * D_O * H_O * NPAIR;   // 119,040
    if (idx >= total) return;
    int tw = idx & (NPAIR - 1);     // pair index: wo = 2*tw
    int t  = idx >> 4;
    int ho = t % H_O;
    t     /= H_O;
    int dd = t % D_O;
    int bc = t / D_O;
    int wo = tw * 2;

    const float* xb = x + (size_t)bc * L_IN * SP_IN
                        + (2 * dd) * (H_IN * W_IN)
                        + (2 * ho) * W_IN + 4 * tw;

    // Spatial 3x3x3 sums for both wo columns, all 16 frames.
    float sA[L_IN], sB[L_IN];
    #pragma unroll
    for (int l = 0; l < L_IN; ++l) {
        const float* fb = xb + (size_t)l * SP_IN;
        float a0 = 0.0f, a1 = 0.0f;
        #pragma unroll
        for (int kd = 0; kd < 3; ++kd) {
            #pragma unroll
            for (int kh = 0; kh < 3; ++kh) {
                const float* p = fb + kd * (H_IN * W_IN) + kh * W_IN;
                float4 v = *reinterpret_cast<const float4*>(p);  // 16B aligned
                float  b = p[4];   // may read past row for tw=15; in-bounds
                                   // garbage, result discarded (wo+1==31)
                a0 += v.x + v.y + v.z;
                a1 += v.z + v.w + b;
            }
        }
        sA[l] = a0; sB[l] = a1;
    }

    // Temporal sliding window (k=3, stride=1) + scale; streaming stores.
    int sp = (dd * H_O + ho) * W_O + wo;
    float* op = out + (size_t)bc * L_O * SP_OUT + sp;
    const float inv = 1.0f / 81.0f;
    bool second = (wo + 1 < W_O);
    #pragma unroll
    for (int lo = 0; lo < L_O; ++lo) {
        __builtin_nontemporal_store((sA[lo] + sA[lo + 1] + sA[lo + 2]) * inv,
                                    &op[(size_t)lo * SP_OUT]);
        if (second)
            __builtin_nontemporal_store((sB[lo] + sB[lo + 1] + sB[lo + 2]) * inv,
                                        &op[(size_t)lo * SP_OUT + 1]);
    }
}

extern "C" void kernel_launch(void* const* d_in, const int* in_sizes, int n_in,
                              void* d_out, int out_size, void* d_ws, size_t ws_size,
                              hipStream_t stream) {
    const float* x = (const float*)d_in[0];
    float* out = (float*)d_out;
    (void)d_ws; (void)ws_size;

    int total = BC * D_O * H_O * NPAIR;
    int block = 256;
    int grid = (total + block - 1) / block;   // 465
    pool4d_pair<<<grid, block, 0, stream>>>(x, out);
}

// Round 6
// 28.140 us; speedup vs baseline: 3.6442x; 3.6442x over previous
//
#include <hip/hip_runtime.h>

// Pool4d: x [b=2, c=8, l=16, d=32, h=64, w=64] f32
// kernel (3,3,3,3), stride (1,2,2,2), VALID, divide by 81.
// out [2, 8, 14, 15, 31, 31] f32.
//
// R6 = R4 structure (one thread per output spatial site, full-l fusion,
// XCD-chunked bijective swizzle, NT stores) with the 3-float w-window
// loaded as ONE 16B load (8B-aligned, via memcpy -> global_load_dwordx4,
// 4th lane dead). Halves VMEM instruction count vs float2+scalar with no
// extra live registers (R5 lesson: VGPR=256 spill disaster from paired-wo).

#define BC   16          // b*c
#define L_IN 16
#define D_IN 32
#define H_IN 64
#define W_IN 64
#define L_O  14
#define D_O  15
#define H_O  31
#define W_O  31
#define SP_OUT (D_O * H_O * W_O)     // 14415
#define SP_IN  (D_IN * H_IN * W_IN)  // 131072
#define NXCD 8

__global__ __launch_bounds__(256)
void pool4d_fused_x4(const float* __restrict__ x, float* __restrict__ out) {
    // Bijective XCD-chunked swizzle (m204).
    int nwg = gridDim.x;
    int xcd = blockIdx.x % NXCD;
    int pos = blockIdx.x / NXCD;
    int q = nwg / NXCD, r = nwg % NXCD;
    int wg = (xcd < r ? xcd * (q + 1) : r * (q + 1) + (xcd - r) * q) + pos;

    int idx = wg * blockDim.x + threadIdx.x;
    const int total = BC * SP_OUT;          // 230,640
    if (idx >= total) return;
    int wo = idx % W_O;
    int t  = idx / W_O;
    int ho = t % H_O;
    t     /= H_O;
    int dd = t % D_O;
    int bc = t / D_O;

    const float* xb = x + (size_t)bc * L_IN * SP_IN
                        + (size_t)(2 * dd) * (H_IN * W_IN)
                        + (2 * ho) * W_IN + 2 * wo;

    // Spatial 3x3x3 sums for all 16 frames (static indexing).
    float s[L_IN];
    #pragma unroll
    for (int l = 0; l < L_IN; ++l) {
        const float* fb = xb + (size_t)l * SP_IN;
        float acc = 0.0f;
        #pragma unroll
        for (int kd = 0; kd < 3; ++kd) {
            #pragma unroll
            for (int kh = 0; kh < 3; ++kh) {
                const float* p = fb + kd * (H_IN * W_IN) + kh * W_IN;
                float4 v;
                __builtin_memcpy(&v, p, 16);   // 16B load @8B align; max idx 63, in-bounds
                acc += v.x + v.y + v.z;        // v.w dead
            }
        }
        s[l] = acc;
    }

    // Temporal sliding window (k=3, stride=1) + scale; streaming stores.
    int sp = (dd * H_O + ho) * W_O + wo;
    float* op = out + (size_t)bc * L_O * SP_OUT + sp;
    const float inv = 1.0f / 81.0f;
    #pragma unroll
    for (int lo = 0; lo < L_O; ++lo)
        __builtin_nontemporal_store((s[lo] + s[lo + 1] + s[lo + 2]) * inv,
                                    &op[(size_t)lo * SP_OUT]);
}

extern "C" void kernel_launch(void* const* d_in, const int* in_sizes, int n_in,
                              void* d_out, int out_size, void* d_ws, size_t ws_size,
                              hipStream_t stream) {
    const float* x = (const float*)d_in[0];
    float* out = (float*)d_out;
    (void)d_ws; (void)ws_size;

    int total = BC * SP_OUT;
    int block = 256;
    int grid = (total + block - 1) / block;   // 901
    pool4d_fused_x4<<<grid, block, 0, stream>>>(x, out);
}

// Round 7
// 27.705 us; speedup vs baseline: 3.7014x; 1.0157x over previous
//
#include <hip/hip_runtime.h>

// Pool4d: x [b=2, c=8, l=16, d=32, h=64, w=64] f32
// kernel (3,3,3,3), stride (1,2,2,2), VALID, divide by 81.
// out [2, 8, 14, 15, 31, 31] f32.
//
// R7 = R6 minus the nontemporal store hint. Output rows are 124B
// (31 floats) -> never cache-line aligned; NT (no-allocate) stores force
// partial-line RMW fetches from HBM (~+13MB FETCH). Normal stores coalesce
// in L2 and write back full lines. Everything else unchanged:
// one thread per output spatial site, full-l fusion, dwordx4 window loads,
// XCD-chunked bijective swizzle.

#define BC   16          // b*c
#define L_IN 16
#define D_IN 32
#define H_IN 64
#define W_IN 64
#define L_O  14
#define D_O  15
#define H_O  31
#define W_O  31
#define SP_OUT (D_O * H_O * W_O)     // 14415
#define SP_IN  (D_IN * H_IN * W_IN)  // 131072
#define NXCD 8

__global__ __launch_bounds__(256)
void pool4d_fused_x4s(const float* __restrict__ x, float* __restrict__ out) {
    // Bijective XCD-chunked swizzle (m204).
    int nwg = gridDim.x;
    int xcd = blockIdx.x % NXCD;
    int pos = blockIdx.x / NXCD;
    int q = nwg / NXCD, r = nwg % NXCD;
    int wg = (xcd < r ? xcd * (q + 1) : r * (q + 1) + (xcd - r) * q) + pos;

    int idx = wg * blockDim.x + threadIdx.x;
    const int total = BC * SP_OUT;          // 230,640
    if (idx >= total) return;
    int wo = idx % W_O;
    int t  = idx / W_O;
    int ho = t % H_O;
    t     /= H_O;
    int dd = t % D_O;
    int bc = t / D_O;

    const float* xb = x + (size_t)bc * L_IN * SP_IN
                        + (size_t)(2 * dd) * (H_IN * W_IN)
                        + (2 * ho) * W_IN + 2 * wo;

    // Spatial 3x3x3 sums for all 16 frames (static indexing).
    float s[L_IN];
    #pragma unroll
    for (int l = 0; l < L_IN; ++l) {
        const float* fb = xb + (size_t)l * SP_IN;
        float acc = 0.0f;
        #pragma unroll
        for (int kd = 0; kd < 3; ++kd) {
            #pragma unroll
            for (int kh = 0; kh < 3; ++kh) {
                const float* p = fb + kd * (H_IN * W_IN) + kh * W_IN;
                float4 v;
                __builtin_memcpy(&v, p, 16);   // 16B load @8B align; max idx 63, in-bounds
                acc += v.x + v.y + v.z;        // v.w dead
            }
        }
        s[l] = acc;
    }

    // Temporal sliding window (k=3, stride=1) + scale; normal stores
    // (L2-allocating -> full-line writebacks, no RMW fetch).
    int sp = (dd * H_O + ho) * W_O + wo;
    float* op = out + (size_t)bc * L_O * SP_OUT + sp;
    const float inv = 1.0f / 81.0f;
    #pragma unroll
    for (int lo = 0; lo < L_O; ++lo)
        op[(size_t)lo * SP_OUT] = (s[lo] + s[lo + 1] + s[lo + 2]) * inv;
}

extern "C" void kernel_launch(void* const* d_in, const int* in_sizes, int n_in,
                              void* d_out, int out_size, void* d_ws, size_t ws_size,
                              hipStream_t stream) {
    const float* x = (const float*)d_in[0];
    float* out = (float*)d_out;
    (void)d_ws; (void)ws_size;

    int total = BC * SP_OUT;
    int block = 256;
    int grid = (total + block - 1) / block;   // 901
    pool4d_fused_x4s<<<grid, block, 0, stream>>>(x, out);
}

// Round 8
// 27.332 us; speedup vs baseline: 3.7519x; 1.0137x over previous
//
#include <hip/hip_runtime.h>

// Pool4d: x [b=2, c=8, l=16, d=32, h=64, w=64] f32
// kernel (3,3,3,3), stride (1,2,2,2), VALID, divide by 81.
// out [2, 8, 14, 15, 31, 31] f32.
//
// R8 = R7 body with block=64, grid=3604 (was 256/901). With 901 blocks,
// CUs get 3 vs 4 co-resident blocks -> 14% work imbalance, HBM drain-tail.
// 64-thread blocks give 14.08 blocks/CU -> imbalance ~7%. Body unchanged:
// one thread per output spatial site, full-l fusion, dwordx4 window loads,
// XCD-chunked bijective swizzle, normal (L2-allocating) stores.

#define BC   16          // b*c
#define L_IN 16
#define D_IN 32
#define H_IN 64
#define W_IN 64
#define L_O  14
#define D_O  15
#define H_O  31
#define W_O  31
#define SP_OUT (D_O * H_O * W_O)     // 14415
#define SP_IN  (D_IN * H_IN * W_IN)  // 131072
#define NXCD 8
#define BLK  64

__global__ __launch_bounds__(BLK)
void pool4d_fused_b64(const float* __restrict__ x, float* __restrict__ out) {
    // Bijective XCD-chunked swizzle (m204).
    int nwg = gridDim.x;
    int xcd = blockIdx.x % NXCD;
    int pos = blockIdx.x / NXCD;
    int q = nwg / NXCD, r = nwg % NXCD;
    int wg = (xcd < r ? xcd * (q + 1) : r * (q + 1) + (xcd - r) * q) + pos;

    int idx = wg * BLK + threadIdx.x;
    const int total = BC * SP_OUT;          // 230,640
    if (idx >= total) return;
    int wo = idx % W_O;
    int t  = idx / W_O;
    int ho = t % H_O;
    t     /= H_O;
    int dd = t % D_O;
    int bc = t / D_O;

    const float* xb = x + (size_t)bc * L_IN * SP_IN
                        + (size_t)(2 * dd) * (H_IN * W_IN)
                        + (2 * ho) * W_IN + 2 * wo;

    // Spatial 3x3x3 sums for all 16 frames (static indexing).
    float s[L_IN];
    #pragma unroll
    for (int l = 0; l < L_IN; ++l) {
        const float* fb = xb + (size_t)l * SP_IN;
        float acc = 0.0f;
        #pragma unroll
        for (int kd = 0; kd < 3; ++kd) {
            #pragma unroll
            for (int kh = 0; kh < 3; ++kh) {
                const float* p = fb + kd * (H_IN * W_IN) + kh * W_IN;
                float4 v;
                __builtin_memcpy(&v, p, 16);   // 16B load @8B align; max idx 63, in-bounds
                acc += v.x + v.y + v.z;        // v.w dead
            }
        }
        s[l] = acc;
    }

    // Temporal sliding window (k=3, stride=1) + scale; normal stores.
    int sp = (dd * H_O + ho) * W_O + wo;
    float* op = out + (size_t)bc * L_O * SP_OUT + sp;
    const float inv = 1.0f / 81.0f;
    #pragma unroll
    for (int lo = 0; lo < L_O; ++lo)
        op[(size_t)lo * SP_OUT] = (s[lo] + s[lo + 1] + s[lo + 2]) * inv;
}

extern "C" void kernel_launch(void* const* d_in, const int* in_sizes, int n_in,
                              void* d_out, int out_size, void* d_ws, size_t ws_size,
                              hipStream_t stream) {
    const float* x = (const float*)d_in[0];
    float* out = (float*)d_out;
    (void)d_ws; (void)ws_size;

    int total = BC * SP_OUT;
    int grid = (total + BLK - 1) / BLK;     // 3604
    pool4d_fused_b64<<<grid, BLK, 0, stream>>>(x, out);
}